// Round 3
// baseline (2242.824 us; speedup 1.0000x reference)
//
#include <hip/hip_runtime.h>

#define N_NODES 100000
#define N_EDGES 1600000
#define IN_F 128
#define HID_F 64
#define OUT_F 40
#define N_STEPS 10

static constexpr float DT = 0.1f;
static constexpr float ONE_MINUS_DT = 0.9f;
// SIGMA * sqrt(DT) = 0.01 * sqrt(0.1)
static constexpr float C_NOISE = 0.0031622776601683794f;

// ---------------- degree histograms (int) ----------------
__global__ __launch_bounds__(256) void deg_kernel(const int* __restrict__ src,
                                                  const int* __restrict__ dst,
                                                  int* __restrict__ deg_out,
                                                  int* __restrict__ deg_in) {
    int i = blockIdx.x * 256 + threadIdx.x;
    if (i < N_EDGES) {
        atomicAdd(&deg_out[src[i]], 1);
        atomicAdd(&deg_in[dst[i]], 1);
    }
}

// ---------------- per-node scale factors ----------------
__global__ __launch_bounds__(256) void scale_kernel(const int* __restrict__ deg_out,
                                                    const int* __restrict__ deg_in,
                                                    float* __restrict__ a,
                                                    float* __restrict__ b) {
    int i = blockIdx.x * 256 + threadIdx.x;
    if (i < N_NODES) {
        a[i] = rsqrtf((float)max(deg_out[i], 1));
        b[i] = rsqrtf((float)max(deg_in[i], 1));
    }
}

// ---------------- 3-kernel exclusive scan of deg_in -> row_ptr ----------------
__global__ __launch_bounds__(256) void scan_blocksum_kernel(const int* __restrict__ deg,
                                                            int* __restrict__ blocksum) {
    __shared__ int buf[256];
    int i = blockIdx.x * 256 + threadIdx.x;
    buf[threadIdx.x] = (i < N_NODES) ? deg[i] : 0;
    __syncthreads();
    for (int off = 128; off > 0; off >>= 1) {
        if (threadIdx.x < off) buf[threadIdx.x] += buf[threadIdx.x + off];
        __syncthreads();
    }
    if (threadIdx.x == 0) blocksum[blockIdx.x] = buf[0];
}

__global__ __launch_bounds__(512) void scan_top_kernel(const int* __restrict__ blocksum,
                                                       int* __restrict__ blockpfx,
                                                       int nblocks) {
    __shared__ int buf[512];
    int v = (threadIdx.x < nblocks) ? blocksum[threadIdx.x] : 0;
    buf[threadIdx.x] = v;
    __syncthreads();
    for (int off = 1; off < 512; off <<= 1) {
        int t = (threadIdx.x >= off) ? buf[threadIdx.x - off] : 0;
        __syncthreads();
        buf[threadIdx.x] += t;
        __syncthreads();
    }
    if (threadIdx.x < nblocks) blockpfx[threadIdx.x] = buf[threadIdx.x] - v;
}

__global__ __launch_bounds__(256) void scan_final_kernel(const int* __restrict__ deg,
                                                         const int* __restrict__ blockpfx,
                                                         int* __restrict__ row_ptr,
                                                         int* __restrict__ cursor) {
    __shared__ int buf[256];
    int i = blockIdx.x * 256 + threadIdx.x;
    int v = (i < N_NODES) ? deg[i] : 0;
    buf[threadIdx.x] = v;
    __syncthreads();
    for (int off = 1; off < 256; off <<= 1) {
        int t = (threadIdx.x >= off) ? buf[threadIdx.x - off] : 0;
        __syncthreads();
        buf[threadIdx.x] += t;
        __syncthreads();
    }
    int excl = blockpfx[blockIdx.x] + buf[threadIdx.x] - v;
    if (i < N_NODES) {
        row_ptr[i] = excl;
        cursor[i] = excl;
    }
    if (blockIdx.x == gridDim.x - 1 && threadIdx.x == 255)
        row_ptr[N_NODES] = blockpfx[blockIdx.x] + buf[255];
}

// ---------------- CSR fill: bucket edges by dst ----------------
__global__ __launch_bounds__(256) void fill_kernel(const int* __restrict__ src,
                                                   const int* __restrict__ dst,
                                                   int* __restrict__ cursor,
                                                   int* __restrict__ src_sorted) {
    int e = blockIdx.x * 256 + threadIdx.x;
    if (e < N_EDGES) {
        int pos = atomicAdd(&cursor[dst[e]], 1);
        src_sorted[pos] = src[e];
    }
}

// ---------------- tiled row GEMM: Y[n,64] = (A[n,K] @ W[K,64]) * scale[n]? ----------
// 16 rows per block (4 per wave), lane = output column. A tile + W staged in LDS.
template <int K, bool SCALE>
__global__ __launch_bounds__(256) void rowmm_tiled_kernel(const float* __restrict__ A,
                                                          const float* __restrict__ W,
                                                          float* __restrict__ Y,
                                                          const float* __restrict__ scale) {
    __shared__ float wlds[K * HID_F];
    __shared__ float alds[16 * K];
    for (int i = threadIdx.x; i < K * HID_F / 4; i += 256)
        reinterpret_cast<float4*>(wlds)[i] = reinterpret_cast<const float4*>(W)[i];
    const float* ablk = A + (size_t)blockIdx.x * 16 * K;
    for (int i = threadIdx.x; i < 16 * K / 4; i += 256)
        reinterpret_cast<float4*>(alds)[i] = reinterpret_cast<const float4*>(ablk)[i];
    __syncthreads();

    int wid = threadIdx.x >> 6;
    int lane = threadIdx.x & 63;
    int r0 = wid * 4;  // local row base for this wave

    float acc[4] = {0.f, 0.f, 0.f, 0.f};
#pragma unroll 4
    for (int k = 0; k < K; k += 4) {
        float w0 = wlds[(k + 0) * HID_F + lane];
        float w1 = wlds[(k + 1) * HID_F + lane];
        float w2 = wlds[(k + 2) * HID_F + lane];
        float w3 = wlds[(k + 3) * HID_F + lane];
#pragma unroll
        for (int i = 0; i < 4; i++) {
            float4 av = *reinterpret_cast<const float4*>(&alds[(r0 + i) * K + k]);
            acc[i] += av.x * w0 + av.y * w1 + av.z * w2 + av.w * w3;
        }
    }

    size_t grow = (size_t)blockIdx.x * 16 + r0;
#pragma unroll
    for (int i = 0; i < 4; i++) {
        float v = acc[i];
        if (SCALE) v *= scale[grow + i];
        Y[(grow + i) * HID_F + lane] = v;
    }
}

// ---------------- fused step: gather + Euler-Maruyama + next-step msg GEMM -------
// 16 nodes per block, one wave per node x 4 sequential nodes; lane = feature.
// x[d]   = 0.9*x[d] + 0.1*b[d]*sum_{e in CSR[d]} m_prev[src_e] + C_NOISE*dW[d]
// m_next[d] = a[d] * (x_new[d] @ W_msg)          (skipped on last step)
template <bool LAST>
__global__ __launch_bounds__(256) void step_kernel(const float* __restrict__ mprev,
                                                   float* __restrict__ mnext,
                                                   const float* __restrict__ Wmsg,
                                                   const int* __restrict__ row_ptr,
                                                   const int* __restrict__ src_sorted,
                                                   const float* __restrict__ a,
                                                   const float* __restrict__ b,
                                                   float* __restrict__ x,
                                                   const float* __restrict__ dw) {
    __shared__ float wlds[HID_F * HID_F];
    if (!LAST) {
        for (int i = threadIdx.x; i < HID_F * HID_F / 4; i += 256)
            reinterpret_cast<float4*>(wlds)[i] = reinterpret_cast<const float4*>(Wmsg)[i];
        __syncthreads();
    }

    int wid = threadIdx.x >> 6;
    int lane = threadIdx.x & 63;

#pragma unroll 1
    for (int t = 0; t < 4; t++) {
        int d = blockIdx.x * 16 + wid * 4 + t;
        int beg = row_ptr[d];
        int end = row_ptr[d + 1];

        float acc0 = 0.f, acc1 = 0.f, acc2 = 0.f, acc3 = 0.f;
        int j = beg;
        while (j < end) {
            int cnt = min(end - j, 64);
            int idx = (lane < cnt) ? src_sorted[j + lane] : 0;
            int jj = 0;
            for (; jj + 4 <= cnt; jj += 4) {
                int s0 = __shfl(idx, jj + 0);
                int s1 = __shfl(idx, jj + 1);
                int s2 = __shfl(idx, jj + 2);
                int s3 = __shfl(idx, jj + 3);
                acc0 += mprev[(size_t)s0 * HID_F + lane];
                acc1 += mprev[(size_t)s1 * HID_F + lane];
                acc2 += mprev[(size_t)s2 * HID_F + lane];
                acc3 += mprev[(size_t)s3 * HID_F + lane];
            }
            for (; jj < cnt; ++jj)
                acc0 += mprev[(size_t)__shfl(idx, jj) * HID_F + lane];
            j += cnt;
        }
        float acc = (acc0 + acc1) + (acc2 + acc3);

        size_t o = (size_t)d * HID_F + lane;
        float xn = ONE_MINUS_DT * x[o] + (DT * b[d]) * acc + C_NOISE * dw[o];
        x[o] = xn;

        if (!LAST) {
            float mm = 0.f;
#pragma unroll
            for (int k = 0; k < HID_F; k++)
                mm += __shfl(xn, k) * wlds[k * HID_F + lane];
            mnext[o] = a[d] * mm;
        }
    }
}

// ---------------- out projection: out[n,40] = x[n,64] @ W_out[64,40] ----------------
__global__ __launch_bounds__(256) void out_proj_kernel(const float* __restrict__ x,
                                                       const float* __restrict__ W,
                                                       float* __restrict__ out) {
    __shared__ float w[HID_F * OUT_F];
    for (int i = threadIdx.x; i < HID_F * OUT_F; i += 256) w[i] = W[i];
    __syncthreads();

    int i = blockIdx.x * 256 + threadIdx.x;  // over N*40 = 4M
    if (i >= N_NODES * OUT_F) return;
    int r = i / OUT_F;
    int j = i - r * OUT_F;
    const float* xr = x + (size_t)r * HID_F;
    float acc = 0.0f;
#pragma unroll
    for (int k = 0; k < HID_F; k++) acc += xr[k] * w[k * OUT_F + j];
    out[i] = acc;
}

extern "C" void kernel_launch(void* const* d_in, const int* in_sizes, int n_in,
                              void* d_out, int out_size, void* d_ws, size_t ws_size,
                              hipStream_t stream) {
    const float* h     = (const float*)d_in[0];
    const float* W_in  = (const float*)d_in[1];
    const float* W_msg = (const float*)d_in[2];
    const float* W_out = (const float*)d_in[3];
    const float* dW    = (const float*)d_in[4];
    const int*   src   = (const int*)d_in[5];
    const int*   dst   = (const int*)d_in[6];
    float* out = (float*)d_out;

    const size_t NH = (size_t)N_NODES * HID_F;  // 6.4M
    const int NBLK = (N_NODES + 255) / 256;     // 391

    float* x       = (float*)d_ws;              // 6.4M f
    float* m0      = x + NH;                    // 6.4M f
    float* m1      = m0 + NH;                   // 6.4M f
    float* a       = m1 + NH;                   // 100K f
    float* b       = a + N_NODES;               // 100K f
    int* deg_out_i = (int*)(b + N_NODES);       // 100K i
    int* deg_in_i  = deg_out_i + N_NODES;       // 100K i
    int* row_ptr   = deg_in_i + N_NODES;        // 100K+1 i
    int* cursor    = row_ptr + N_NODES + 1;     // 100K+1 i
    int* blocksum  = cursor + N_NODES + 1;      // 391 i
    int* blockpfx  = blocksum + 512;            // 391 i
    int* src_sorted= blockpfx + 512;            // 1.6M i

    // ---- one-time per launch: degrees, scales, CSR ----
    hipMemsetAsync(deg_out_i, 0, 2 * N_NODES * sizeof(int), stream);
    {
        dim3 ge((N_EDGES + 255) / 256);
        deg_kernel<<<ge, 256, 0, stream>>>(src, dst, deg_out_i, deg_in_i);
        scale_kernel<<<dim3(NBLK), 256, 0, stream>>>(deg_out_i, deg_in_i, a, b);
        scan_blocksum_kernel<<<dim3(NBLK), 256, 0, stream>>>(deg_in_i, blocksum);
        scan_top_kernel<<<1, 512, 0, stream>>>(blocksum, blockpfx, NBLK);
        scan_final_kernel<<<dim3(NBLK), 256, 0, stream>>>(deg_in_i, blockpfx, row_ptr, cursor);
        fill_kernel<<<ge, 256, 0, stream>>>(src, dst, cursor, src_sorted);
    }

    const dim3 g_tile(N_NODES / 16);  // 6250

    // ---- x = h @ W_in ----
    rowmm_tiled_kernel<IN_F, false><<<g_tile, 256, 0, stream>>>(h, W_in, x, nullptr);
    // ---- m0 = (x @ W_msg) * a ----
    rowmm_tiled_kernel<HID_F, true><<<g_tile, 256, 0, stream>>>(x, W_msg, m0, a);

    // ---- 10 fused Euler-Maruyama steps (double-buffered m) ----
    float* mbuf[2] = {m0, m1};
    for (int k = 0; k < N_STEPS; k++) {
        const float* mp = mbuf[k & 1];
        float* mn = mbuf[(k + 1) & 1];
        const float* dwk = dW + (size_t)k * NH;
        if (k < N_STEPS - 1)
            step_kernel<false><<<g_tile, 256, 0, stream>>>(mp, mn, W_msg, row_ptr,
                                                           src_sorted, a, b, x, dwk);
        else
            step_kernel<true><<<g_tile, 256, 0, stream>>>(mp, mn, W_msg, row_ptr,
                                                          src_sorted, a, b, x, dwk);
    }

    // ---- out = x @ W_out ----
    out_proj_kernel<<<dim3((N_NODES * OUT_F + 255) / 256), 256, 0, stream>>>(x, W_out, out);
}

// Round 4
// 1316.525 us; speedup vs baseline: 1.7036x; 1.7036x over previous
//
#include <hip/hip_runtime.h>

#define N_NODES 100000
#define N_EDGES 1600000
#define IN_F 128
#define HID_F 64
#define OUT_F 40
#define N_STEPS 10

static constexpr float DT = 0.1f;
static constexpr float ONE_MINUS_DT = 0.9f;
// SIGMA * sqrt(DT) = 0.01 * sqrt(0.1)
static constexpr float C_NOISE = 0.0031622776601683794f;

// ---------------- degree histograms (int) ----------------
__global__ __launch_bounds__(256) void deg_kernel(const int* __restrict__ src,
                                                  const int* __restrict__ dst,
                                                  int* __restrict__ deg_out,
                                                  int* __restrict__ deg_in) {
    int i = blockIdx.x * 256 + threadIdx.x;
    if (i < N_EDGES) {
        atomicAdd(&deg_out[src[i]], 1);
        atomicAdd(&deg_in[dst[i]], 1);
    }
}

// ---------------- per-node scale factors ----------------
__global__ __launch_bounds__(256) void scale_kernel(const int* __restrict__ deg_out,
                                                    const int* __restrict__ deg_in,
                                                    float* __restrict__ a,
                                                    float* __restrict__ b) {
    int i = blockIdx.x * 256 + threadIdx.x;
    if (i < N_NODES) {
        a[i] = rsqrtf((float)max(deg_out[i], 1));
        b[i] = rsqrtf((float)max(deg_in[i], 1));
    }
}

// ---------------- 3-kernel exclusive scan of deg_in -> row_ptr ----------------
__global__ __launch_bounds__(256) void scan_blocksum_kernel(const int* __restrict__ deg,
                                                            int* __restrict__ blocksum) {
    __shared__ int buf[256];
    int i = blockIdx.x * 256 + threadIdx.x;
    buf[threadIdx.x] = (i < N_NODES) ? deg[i] : 0;
    __syncthreads();
    for (int off = 128; off > 0; off >>= 1) {
        if (threadIdx.x < off) buf[threadIdx.x] += buf[threadIdx.x + off];
        __syncthreads();
    }
    if (threadIdx.x == 0) blocksum[blockIdx.x] = buf[0];
}

__global__ __launch_bounds__(512) void scan_top_kernel(const int* __restrict__ blocksum,
                                                       int* __restrict__ blockpfx,
                                                       int nblocks) {
    __shared__ int buf[512];
    int v = (threadIdx.x < nblocks) ? blocksum[threadIdx.x] : 0;
    buf[threadIdx.x] = v;
    __syncthreads();
    for (int off = 1; off < 512; off <<= 1) {
        int t = (threadIdx.x >= off) ? buf[threadIdx.x - off] : 0;
        __syncthreads();
        buf[threadIdx.x] += t;
        __syncthreads();
    }
    if (threadIdx.x < nblocks) blockpfx[threadIdx.x] = buf[threadIdx.x] - v;
}

__global__ __launch_bounds__(256) void scan_final_kernel(const int* __restrict__ deg,
                                                         const int* __restrict__ blockpfx,
                                                         int* __restrict__ row_ptr,
                                                         int* __restrict__ cursor) {
    __shared__ int buf[256];
    int i = blockIdx.x * 256 + threadIdx.x;
    int v = (i < N_NODES) ? deg[i] : 0;
    buf[threadIdx.x] = v;
    __syncthreads();
    for (int off = 1; off < 256; off <<= 1) {
        int t = (threadIdx.x >= off) ? buf[threadIdx.x - off] : 0;
        __syncthreads();
        buf[threadIdx.x] += t;
        __syncthreads();
    }
    int excl = blockpfx[blockIdx.x] + buf[threadIdx.x] - v;
    if (i < N_NODES) {
        row_ptr[i] = excl;
        cursor[i] = excl;
    }
    if (blockIdx.x == gridDim.x - 1 && threadIdx.x == 255)
        row_ptr[N_NODES] = blockpfx[blockIdx.x] + buf[255];
}

// ---------------- CSR fill: bucket edges by dst ----------------
__global__ __launch_bounds__(256) void fill_kernel(const int* __restrict__ src,
                                                   const int* __restrict__ dst,
                                                   int* __restrict__ cursor,
                                                   int* __restrict__ src_sorted) {
    int e = blockIdx.x * 256 + threadIdx.x;
    if (e < N_EDGES) {
        int pos = atomicAdd(&cursor[dst[e]], 1);
        src_sorted[pos] = src[e];
    }
}

// ---------------- register-W row GEMM ----------------
// Y[r, 0..NCOL) = (A[r, 0..K) @ W[K, NCOL]) * (SCALE ? scale[r] : 1)
// One wave per RPW rows. Lane j holds column j of W in VGPRs (wreg[K]).
// A-row elements are wave-uniform -> scalar (SGPR) loads; pure v_fma with
// SGPR operand; zero LDS, zero shuffles. 4 rows interleaved for ILP.
template <int K, int NCOL, int RPW, bool SCALE>
__global__ __launch_bounds__(256) void regw_mm_kernel(const float* __restrict__ A,
                                                      const float* __restrict__ W,
                                                      float* __restrict__ Y,
                                                      const float* __restrict__ scale,
                                                      int nwaves) {
    int lane = threadIdx.x & 63;
    int wid = __builtin_amdgcn_readfirstlane((blockIdx.x * 256 + threadIdx.x) >> 6);
    if (wid >= nwaves) return;

    float wreg[K];
#pragma unroll
    for (int k = 0; k < K; k++)
        wreg[k] = (lane < NCOL) ? W[k * NCOL + lane] : 0.0f;

    int r0 = wid * RPW;
#pragma unroll 1
    for (int rr = 0; rr < RPW; rr += 4) {
        int r = r0 + rr;
        const float* a0 = A + (size_t)(r + 0) * K;
        const float* a1 = A + (size_t)(r + 1) * K;
        const float* a2 = A + (size_t)(r + 2) * K;
        const float* a3 = A + (size_t)(r + 3) * K;
        float acc0 = 0.f, acc1 = 0.f, acc2 = 0.f, acc3 = 0.f;
#pragma unroll
        for (int k = 0; k < K; k++) {
            float w = wreg[k];
            acc0 = fmaf(a0[k], w, acc0);
            acc1 = fmaf(a1[k], w, acc1);
            acc2 = fmaf(a2[k], w, acc2);
            acc3 = fmaf(a3[k], w, acc3);
        }
        if (lane < NCOL) {
            if (SCALE) {
                acc0 *= scale[r + 0];
                acc1 *= scale[r + 1];
                acc2 *= scale[r + 2];
                acc3 *= scale[r + 3];
            }
            Y[(size_t)(r + 0) * NCOL + lane] = acc0;
            Y[(size_t)(r + 1) * NCOL + lane] = acc1;
            Y[(size_t)(r + 2) * NCOL + lane] = acc2;
            Y[(size_t)(r + 3) * NCOL + lane] = acc3;
        }
    }
}

// ---------------- fused gather + Euler-Maruyama update ----------------
// one wave (64 lanes) per dst node; lane = feature.
// x[d] = 0.9*x[d] + 0.1*b[d]*sum_{e in CSR[d]} m[src_e] + C_NOISE*dW[d]
__global__ __launch_bounds__(256) void gather_update_kernel(const float* __restrict__ m,
                                                            const int* __restrict__ row_ptr,
                                                            const int* __restrict__ src_sorted,
                                                            const float* __restrict__ b,
                                                            float* __restrict__ x,
                                                            const float* __restrict__ dw) {
    int d = blockIdx.x * 4 + (threadIdx.x >> 6);
    int lane = threadIdx.x & 63;
    if (d >= N_NODES) return;

    int beg = row_ptr[d];
    int end = row_ptr[d + 1];

    float acc0 = 0.f, acc1 = 0.f, acc2 = 0.f, acc3 = 0.f;
    int j = beg;
    while (j < end) {
        int cnt = min(end - j, 64);
        int idx = (lane < cnt) ? src_sorted[j + lane] : 0;
        int jj = 0;
        for (; jj + 4 <= cnt; jj += 4) {
            int s0 = __shfl(idx, jj + 0);
            int s1 = __shfl(idx, jj + 1);
            int s2 = __shfl(idx, jj + 2);
            int s3 = __shfl(idx, jj + 3);
            acc0 += m[(size_t)s0 * HID_F + lane];
            acc1 += m[(size_t)s1 * HID_F + lane];
            acc2 += m[(size_t)s2 * HID_F + lane];
            acc3 += m[(size_t)s3 * HID_F + lane];
        }
        for (; jj < cnt; ++jj)
            acc0 += m[(size_t)__shfl(idx, jj) * HID_F + lane];
        j += cnt;
    }
    float acc = (acc0 + acc1) + (acc2 + acc3);

    size_t o = (size_t)d * HID_F + lane;
    float xv = x[o];
    x[o] = ONE_MINUS_DT * xv + (DT * b[d]) * acc + C_NOISE * dw[o];
}

extern "C" void kernel_launch(void* const* d_in, const int* in_sizes, int n_in,
                              void* d_out, int out_size, void* d_ws, size_t ws_size,
                              hipStream_t stream) {
    const float* h     = (const float*)d_in[0];
    const float* W_in  = (const float*)d_in[1];
    const float* W_msg = (const float*)d_in[2];
    const float* W_out = (const float*)d_in[3];
    const float* dW    = (const float*)d_in[4];
    const int*   src   = (const int*)d_in[5];
    const int*   dst   = (const int*)d_in[6];
    float* out = (float*)d_out;

    const size_t NH = (size_t)N_NODES * HID_F;  // 6.4M
    const int NBLK = (N_NODES + 255) / 256;     // 391

    float* x       = (float*)d_ws;              // 6.4M f
    float* m       = x + NH;                    // 6.4M f
    float* a       = m + NH;                    // 100K f
    float* b       = a + N_NODES;               // 100K f
    int* deg_out_i = (int*)(b + N_NODES);       // 100K i
    int* deg_in_i  = deg_out_i + N_NODES;       // 100K i
    int* row_ptr   = deg_in_i + N_NODES;        // 100K+1 i
    int* cursor    = row_ptr + N_NODES + 1;     // 100K+1 i
    int* blocksum  = cursor + N_NODES + 1;      // 391 i
    int* blockpfx  = blocksum + 512;            // 391 i
    int* src_sorted= blockpfx + 512;            // 1.6M i

    // ---- one-time per launch: degrees, scales, CSR ----
    hipMemsetAsync(deg_out_i, 0, 2 * N_NODES * sizeof(int), stream);
    {
        dim3 ge((N_EDGES + 255) / 256);
        deg_kernel<<<ge, 256, 0, stream>>>(src, dst, deg_out_i, deg_in_i);
        scale_kernel<<<dim3(NBLK), 256, 0, stream>>>(deg_out_i, deg_in_i, a, b);
        scan_blocksum_kernel<<<dim3(NBLK), 256, 0, stream>>>(deg_in_i, blocksum);
        scan_top_kernel<<<1, 512, 0, stream>>>(blocksum, blockpfx, NBLK);
        scan_final_kernel<<<dim3(NBLK), 256, 0, stream>>>(deg_in_i, blockpfx, row_ptr, cursor);
        fill_kernel<<<ge, 256, 0, stream>>>(src, dst, cursor, src_sorted);
    }

    // ---- x = h @ W_in ----
    {
        const int nwaves = N_NODES / 16;                // 6250 (RPW=16)
        const int grid = (nwaves + 3) / 4;              // 1563
        regw_mm_kernel<IN_F, HID_F, 16, false><<<dim3(grid), 256, 0, stream>>>(
            h, W_in, x, nullptr, nwaves);
    }

    // ---- 10 Euler-Maruyama steps: m = a*(x@W_msg); x = gather-update ----
    const int nwaves_msg = N_NODES / 8;                 // 12500 (RPW=8)
    const dim3 g_msg((nwaves_msg + 3) / 4);             // 3125
    const dim3 g_gather((N_NODES + 3) / 4);             // 25000
    for (int k = 0; k < N_STEPS; k++) {
        regw_mm_kernel<HID_F, HID_F, 8, true><<<g_msg, 256, 0, stream>>>(
            x, W_msg, m, a, nwaves_msg);
        gather_update_kernel<<<g_gather, 256, 0, stream>>>(m, row_ptr, src_sorted, b, x,
                                                           dW + (size_t)k * NH);
    }

    // ---- out = x @ W_out ----
    {
        const int nwaves = N_NODES / 8;                 // 12500 (RPW=8)
        regw_mm_kernel<HID_F, OUT_F, 8, false><<<dim3((nwaves + 3) / 4), 256, 0, stream>>>(
            x, W_out, out, nullptr, nwaves);
    }
}

// Round 5
// 1301.960 us; speedup vs baseline: 1.7227x; 1.0112x over previous
//
#include <hip/hip_runtime.h>

#define N_NODES 100000
#define N_EDGES 1600000
#define IN_F 128
#define HID_F 64
#define OUT_F 40
#define N_STEPS 10

static constexpr float DT = 0.1f;
static constexpr float ONE_MINUS_DT = 0.9f;
// SIGMA * sqrt(DT) = 0.01 * sqrt(0.1)
static constexpr float C_NOISE = 0.0031622776601683794f;

// ---------------- degree histograms (int) ----------------
__global__ __launch_bounds__(256) void deg_kernel(const int* __restrict__ src,
                                                  const int* __restrict__ dst,
                                                  int* __restrict__ deg_out,
                                                  int* __restrict__ deg_in) {
    int i = blockIdx.x * 256 + threadIdx.x;
    if (i < N_EDGES) {
        atomicAdd(&deg_out[src[i]], 1);
        atomicAdd(&deg_in[dst[i]], 1);
    }
}

// ---------------- per-node scale factors ----------------
__global__ __launch_bounds__(256) void scale_kernel(const int* __restrict__ deg_out,
                                                    const int* __restrict__ deg_in,
                                                    float* __restrict__ a,
                                                    float* __restrict__ b) {
    int i = blockIdx.x * 256 + threadIdx.x;
    if (i < N_NODES) {
        a[i] = rsqrtf((float)max(deg_out[i], 1));
        b[i] = rsqrtf((float)max(deg_in[i], 1));
    }
}

// ---------------- 3-kernel exclusive scan of deg_in -> row_ptr ----------------
__global__ __launch_bounds__(256) void scan_blocksum_kernel(const int* __restrict__ deg,
                                                            int* __restrict__ blocksum) {
    __shared__ int buf[256];
    int i = blockIdx.x * 256 + threadIdx.x;
    buf[threadIdx.x] = (i < N_NODES) ? deg[i] : 0;
    __syncthreads();
    for (int off = 128; off > 0; off >>= 1) {
        if (threadIdx.x < off) buf[threadIdx.x] += buf[threadIdx.x + off];
        __syncthreads();
    }
    if (threadIdx.x == 0) blocksum[blockIdx.x] = buf[0];
}

__global__ __launch_bounds__(512) void scan_top_kernel(const int* __restrict__ blocksum,
                                                       int* __restrict__ blockpfx,
                                                       int nblocks) {
    __shared__ int buf[512];
    int v = (threadIdx.x < nblocks) ? blocksum[threadIdx.x] : 0;
    buf[threadIdx.x] = v;
    __syncthreads();
    for (int off = 1; off < 512; off <<= 1) {
        int t = (threadIdx.x >= off) ? buf[threadIdx.x - off] : 0;
        __syncthreads();
        buf[threadIdx.x] += t;
        __syncthreads();
    }
    if (threadIdx.x < nblocks) blockpfx[threadIdx.x] = buf[threadIdx.x] - v;
}

__global__ __launch_bounds__(256) void scan_final_kernel(const int* __restrict__ deg,
                                                         const int* __restrict__ blockpfx,
                                                         int* __restrict__ row_ptr,
                                                         int* __restrict__ cursor) {
    __shared__ int buf[256];
    int i = blockIdx.x * 256 + threadIdx.x;
    int v = (i < N_NODES) ? deg[i] : 0;
    buf[threadIdx.x] = v;
    __syncthreads();
    for (int off = 1; off < 256; off <<= 1) {
        int t = (threadIdx.x >= off) ? buf[threadIdx.x - off] : 0;
        __syncthreads();
        buf[threadIdx.x] += t;
        __syncthreads();
    }
    int excl = blockpfx[blockIdx.x] + buf[threadIdx.x] - v;
    if (i < N_NODES) {
        row_ptr[i] = excl;
        cursor[i] = excl;
    }
    if (blockIdx.x == gridDim.x - 1 && threadIdx.x == 255)
        row_ptr[N_NODES] = blockpfx[blockIdx.x] + buf[255];
}

// ---------------- CSR fill: bucket edges by dst ----------------
__global__ __launch_bounds__(256) void fill_kernel(const int* __restrict__ src,
                                                   const int* __restrict__ dst,
                                                   int* __restrict__ cursor,
                                                   int* __restrict__ src_sorted) {
    int e = blockIdx.x * 256 + threadIdx.x;
    if (e < N_EDGES) {
        int pos = atomicAdd(&cursor[dst[e]], 1);
        src_sorted[pos] = src[e];
    }
}

// ---------------- register-W row GEMM ----------------
// Y[r, 0..NCOL) = (A[r, 0..K) @ W[K, NCOL]) * (SCALE ? scale[r] : 1)
// One wave per RPW rows. Lane j holds column j of W in VGPRs (wreg[K]).
// A-row elements are wave-uniform -> scalar (SGPR) loads; pure v_fma with
// SGPR operand; zero LDS, zero shuffles. 4 rows interleaved for ILP.
template <int K, int NCOL, int RPW, bool SCALE>
__global__ __launch_bounds__(256) void regw_mm_kernel(const float* __restrict__ A,
                                                      const float* __restrict__ W,
                                                      float* __restrict__ Y,
                                                      const float* __restrict__ scale,
                                                      int nwaves) {
    int lane = threadIdx.x & 63;
    int wid = __builtin_amdgcn_readfirstlane((blockIdx.x * 256 + threadIdx.x) >> 6);
    if (wid >= nwaves) return;

    float wreg[K];
#pragma unroll
    for (int k = 0; k < K; k++)
        wreg[k] = (lane < NCOL) ? W[k * NCOL + lane] : 0.0f;

    int r0 = wid * RPW;
#pragma unroll 1
    for (int rr = 0; rr < RPW; rr += 4) {
        int r = r0 + rr;
        const float* a0 = A + (size_t)(r + 0) * K;
        const float* a1 = A + (size_t)(r + 1) * K;
        const float* a2 = A + (size_t)(r + 2) * K;
        const float* a3 = A + (size_t)(r + 3) * K;
        float acc0 = 0.f, acc1 = 0.f, acc2 = 0.f, acc3 = 0.f;
#pragma unroll
        for (int k = 0; k < K; k++) {
            float w = wreg[k];
            acc0 = fmaf(a0[k], w, acc0);
            acc1 = fmaf(a1[k], w, acc1);
            acc2 = fmaf(a2[k], w, acc2);
            acc3 = fmaf(a3[k], w, acc3);
        }
        if (lane < NCOL) {
            if (SCALE) {
                acc0 *= scale[r + 0];
                acc1 *= scale[r + 1];
                acc2 *= scale[r + 2];
                acc3 *= scale[r + 3];
            }
            Y[(size_t)(r + 0) * NCOL + lane] = acc0;
            Y[(size_t)(r + 1) * NCOL + lane] = acc1;
            Y[(size_t)(r + 2) * NCOL + lane] = acc2;
            Y[(size_t)(r + 3) * NCOL + lane] = acc3;
        }
    }
}

// ---------------- fused gather + Euler-Maruyama update ----------------
// one wave (64 lanes) per dst node; lane = feature.
// x[d] = 0.9*x[d] + 0.1*b[d]*sum_{e in CSR[d]} m[src_e] + C_NOISE*dW[d]
__global__ __launch_bounds__(256) void gather_update_kernel(const float* __restrict__ m,
                                                            const int* __restrict__ row_ptr,
                                                            const int* __restrict__ src_sorted,
                                                            const float* __restrict__ b,
                                                            float* __restrict__ x,
                                                            const float* __restrict__ dw) {
    int d = blockIdx.x * 4 + (threadIdx.x >> 6);
    int lane = threadIdx.x & 63;
    if (d >= N_NODES) return;

    int beg = row_ptr[d];
    int end = row_ptr[d + 1];

    float acc0 = 0.f, acc1 = 0.f, acc2 = 0.f, acc3 = 0.f;
    int j = beg;
    while (j < end) {
        int cnt = min(end - j, 64);
        int idx = (lane < cnt) ? src_sorted[j + lane] : 0;
        int jj = 0;
        for (; jj + 4 <= cnt; jj += 4) {
            int s0 = __shfl(idx, jj + 0);
            int s1 = __shfl(idx, jj + 1);
            int s2 = __shfl(idx, jj + 2);
            int s3 = __shfl(idx, jj + 3);
            acc0 += m[(size_t)s0 * HID_F + lane];
            acc1 += m[(size_t)s1 * HID_F + lane];
            acc2 += m[(size_t)s2 * HID_F + lane];
            acc3 += m[(size_t)s3 * HID_F + lane];
        }
        for (; jj < cnt; ++jj)
            acc0 += m[(size_t)__shfl(idx, jj) * HID_F + lane];
        j += cnt;
    }
    float acc = (acc0 + acc1) + (acc2 + acc3);

    size_t o = (size_t)d * HID_F + lane;
    float xv = x[o];
    x[o] = ONE_MINUS_DT * xv + (DT * b[d]) * acc + C_NOISE * dw[o];
}

extern "C" void kernel_launch(void* const* d_in, const int* in_sizes, int n_in,
                              void* d_out, int out_size, void* d_ws, size_t ws_size,
                              hipStream_t stream) {
    const float* h     = (const float*)d_in[0];
    const float* W_in  = (const float*)d_in[1];
    const float* W_msg = (const float*)d_in[2];
    const float* W_out = (const float*)d_in[3];
    const float* dW    = (const float*)d_in[4];
    const int*   src   = (const int*)d_in[5];
    const int*   dst   = (const int*)d_in[6];
    float* out = (float*)d_out;

    const size_t NH = (size_t)N_NODES * HID_F;  // 6.4M
    const int NBLK = (N_NODES + 255) / 256;     // 391

    float* x       = (float*)d_ws;              // 6.4M f
    float* m       = x + NH;                    // 6.4M f
    float* a       = m + NH;                    // 100K f
    float* b       = a + N_NODES;               // 100K f
    int* deg_out_i = (int*)(b + N_NODES);       // 100K i
    int* deg_in_i  = deg_out_i + N_NODES;       // 100K i
    int* row_ptr   = deg_in_i + N_NODES;        // 100K+1 i
    int* cursor    = row_ptr + N_NODES + 1;     // 100K+1 i
    int* blocksum  = cursor + N_NODES + 1;      // 391 i
    int* blockpfx  = blocksum + 512;            // 391 i
    int* src_sorted= blockpfx + 512;            // 1.6M i

    // ---- one-time per launch: degrees, scales, CSR ----
    hipMemsetAsync(deg_out_i, 0, 2 * N_NODES * sizeof(int), stream);
    {
        dim3 ge((N_EDGES + 255) / 256);
        deg_kernel<<<ge, 256, 0, stream>>>(src, dst, deg_out_i, deg_in_i);
        scale_kernel<<<dim3(NBLK), 256, 0, stream>>>(deg_out_i, deg_in_i, a, b);
        scan_blocksum_kernel<<<dim3(NBLK), 256, 0, stream>>>(deg_in_i, blocksum);
        scan_top_kernel<<<1, 512, 0, stream>>>(blocksum, blockpfx, NBLK);
        scan_final_kernel<<<dim3(NBLK), 256, 0, stream>>>(deg_in_i, blockpfx, row_ptr, cursor);
        fill_kernel<<<ge, 256, 0, stream>>>(src, dst, cursor, src_sorted);
    }

    // ---- x = h @ W_in ----
    {
        const int nwaves = N_NODES / 16;                // 6250 (RPW=16)
        const int grid = (nwaves + 3) / 4;              // 1563
        regw_mm_kernel<IN_F, HID_F, 16, false><<<dim3(grid), 256, 0, stream>>>(
            h, W_in, x, nullptr, nwaves);
    }

    // ---- 10 Euler-Maruyama steps: m = a*(x@W_msg); x = gather-update ----
    const int nwaves_msg = N_NODES / 8;                 // 12500 (RPW=8)
    const dim3 g_msg((nwaves_msg + 3) / 4);             // 3125
    const dim3 g_gather((N_NODES + 3) / 4);             // 25000
    for (int k = 0; k < N_STEPS; k++) {
        regw_mm_kernel<HID_F, HID_F, 8, true><<<g_msg, 256, 0, stream>>>(
            x, W_msg, m, a, nwaves_msg);
        gather_update_kernel<<<g_gather, 256, 0, stream>>>(m, row_ptr, src_sorted, b, x,
                                                           dW + (size_t)k * NH);
    }

    // ---- out = x @ W_out ----
    {
        const int nwaves = N_NODES / 8;                 // 12500 (RPW=8)
        regw_mm_kernel<HID_F, OUT_F, 8, false><<<dim3((nwaves + 3) / 4), 256, 0, stream>>>(
            x, W_out, out, nullptr, nwaves);
    }
}